// Round 3
// baseline (497.391 us; speedup 1.0000x reference)
//
#include <hip/hip_runtime.h>
#include <math.h>

namespace {

constexpr int B = 64;
constexpr int N = 2048;
constexpr int M = 512;
constexpr float EPS = 1e-8f;

constexpr int THREADS = 256;
constexpr int WAVES = THREADS / 64;          // 4
constexpr int ROWS_PER_BLOCK = 64;
constexpr int ROWS_PER_WAVE = ROWS_PER_BLOCK / WAVES;  // 16
constexpr int CHUNKS_PER_B = N / ROWS_PER_BLOCK;       // 32
constexpr int PF = 4;  // prefetch depth in rows (8 float4 loads in flight)

typedef float vfloat4 __attribute__((ext_vector_type(4)));

// Kernel A: streaming pass over memory.
//   new_mem = memory*(1 - w*e) + w*a   (written out, nontemporal)
//   dots[b,n] = <new_mem[b,n,:], k[b,:]>
//   ss[b,n]   = <new_mem[b,n,:], new_mem[b,n,:]>
//   r[b,m]   += w[b,n]*new_mem[b,n,m]
//
// v3: depth-4 rotating register prefetch (8 loads in flight = 32 VGPRs of
// buffer) + __launch_bounds__(256,4) pinning VGPR<=128 so 16 waves/CU stay
// resident. v2 lesson: unbounded unroll traded TLP (8 waves/CU) for ILP and
// netted ~0. Little's law wants ~140 16B-loads in flight per CU; 16 waves x
// 8 loads = 128 gets there.
__global__ __launch_bounds__(THREADS, 4) void ntm_main(
    const float* __restrict__ memory, const float* __restrict__ w_t,
    const float* __restrict__ e_t, const float* __restrict__ a_t,
    const float* __restrict__ k_t,
    float* __restrict__ r_out, float* __restrict__ new_mem,
    float* __restrict__ dots_ws, float* __restrict__ ss_ws)
{
    const int tid  = threadIdx.x;
    const int lane = tid & 63;
    // Force wave id into an SGPR so w_t/base addresses are provably uniform.
    const int wave = __builtin_amdgcn_readfirstlane(tid >> 6);

    const int b     = blockIdx.x / CHUNKS_PER_B;
    const int chunk = blockIdx.x % CHUNKS_PER_B;
    const int row0  = chunk * ROWS_PER_BLOCK + wave * ROWS_PER_WAVE;

    // Each lane owns 8 m-columns: floats [f0..f0+3] and [f1..f1+3]
    const int f0 = lane * 4;        // covers m 0..255 across the wave
    const int f1 = 256 + lane * 4;  // covers m 256..511

    const size_t bm = (size_t)b * M;
    const vfloat4 e0 = *(const vfloat4*)(e_t + bm + f0);
    const vfloat4 e1 = *(const vfloat4*)(e_t + bm + f1);
    const vfloat4 a0 = *(const vfloat4*)(a_t + bm + f0);
    const vfloat4 a1 = *(const vfloat4*)(a_t + bm + f1);
    const vfloat4 k0 = *(const vfloat4*)(k_t + bm + f0);
    const vfloat4 k1 = *(const vfloat4*)(k_t + bm + f1);

    // Wave-uniform addresses -> scalar loads.
    float wv[ROWS_PER_WAVE];
    #pragma unroll
    for (int i = 0; i < ROWS_PER_WAVE; ++i)
        wv[i] = w_t[(size_t)b * N + row0 + i];

    vfloat4 racc0 = (vfloat4)0.f;
    vfloat4 racc1 = (vfloat4)0.f;

    const size_t base0 = ((size_t)b * N + row0) * (size_t)M;

    // Prologue: fill the 4-row prefetch pipe.
    vfloat4 pm0[PF], pm1[PF];
    #pragma unroll
    for (int i = 0; i < PF; ++i) {
        const size_t base = base0 + (size_t)i * M;
        pm0[i] = *(const vfloat4*)(memory + base + f0);
        pm1[i] = *(const vfloat4*)(memory + base + f1);
    }

    float dpack[4], spack[4];

    #pragma unroll
    for (int i = 0; i < ROWS_PER_WAVE; ++i) {
        const int s = i & 3;                       // compile-time (unrolled)
        const float w = wv[i];
        const size_t base = base0 + (size_t)i * M;

        const vfloat4 m0 = pm0[s];
        const vfloat4 m1 = pm1[s];

        // Refill this pipe slot with row i+PF (stays 8 loads in flight).
        if (i + PF < ROWS_PER_WAVE) {
            const size_t nb = base0 + (size_t)(i + PF) * M;
            pm0[s] = *(const vfloat4*)(memory + nb + f0);
            pm1[s] = *(const vfloat4*)(memory + nb + f1);
        }

        // new = m*(1 - w*e) + w*a = fma(w, fma(-m,e,a), m)
        vfloat4 nm0, nm1;
        nm0.x = fmaf(w, fmaf(-m0.x, e0.x, a0.x), m0.x);
        nm0.y = fmaf(w, fmaf(-m0.y, e0.y, a0.y), m0.y);
        nm0.z = fmaf(w, fmaf(-m0.z, e0.z, a0.z), m0.z);
        nm0.w = fmaf(w, fmaf(-m0.w, e0.w, a0.w), m0.w);
        nm1.x = fmaf(w, fmaf(-m1.x, e1.x, a1.x), m1.x);
        nm1.y = fmaf(w, fmaf(-m1.y, e1.y, a1.y), m1.y);
        nm1.z = fmaf(w, fmaf(-m1.z, e1.z, a1.z), m1.z);
        nm1.w = fmaf(w, fmaf(-m1.w, e1.w, a1.w), m1.w);

        __builtin_nontemporal_store(nm0, (vfloat4*)(new_mem + base + f0));
        __builtin_nontemporal_store(nm1, (vfloat4*)(new_mem + base + f1));

        float dot = nm0.x * k0.x + nm0.y * k0.y + nm0.z * k0.z + nm0.w * k0.w
                  + nm1.x * k1.x + nm1.y * k1.y + nm1.z * k1.z + nm1.w * k1.w;
        float ssv = nm0.x * nm0.x + nm0.y * nm0.y + nm0.z * nm0.z + nm0.w * nm0.w
                  + nm1.x * nm1.x + nm1.y * nm1.y + nm1.z * nm1.z + nm1.w * nm1.w;

        racc0.x = fmaf(w, nm0.x, racc0.x);
        racc0.y = fmaf(w, nm0.y, racc0.y);
        racc0.z = fmaf(w, nm0.z, racc0.z);
        racc0.w = fmaf(w, nm0.w, racc0.w);
        racc1.x = fmaf(w, nm1.x, racc1.x);
        racc1.y = fmaf(w, nm1.y, racc1.y);
        racc1.z = fmaf(w, nm1.z, racc1.z);
        racc1.w = fmaf(w, nm1.w, racc1.w);

        // Per-row wave reduction; load latency is hidden by the prefetch
        // pipe + 16 resident waves, so no need to defer these.
        #pragma unroll
        for (int off = 32; off; off >>= 1) {
            dot += __shfl_xor(dot, off);
            ssv += __shfl_xor(ssv, off);
        }
        dpack[s] = dot;
        spack[s] = ssv;

        if (s == 3 && lane == 0) {
            const int g4 = i - 3;  // first row of this group of 4
            vfloat4 dv = {dpack[0], dpack[1], dpack[2], dpack[3]};
            vfloat4 sv = {spack[0], spack[1], spack[2], spack[3]};
            *(vfloat4*)(dots_ws + (size_t)b * N + row0 + g4) = dv;
            *(vfloat4*)(ss_ws   + (size_t)b * N + row0 + g4) = sv;
        }
    }

    // Combine r partials across the 4 waves in LDS, then one global
    // atomicAdd per element per block (32 blocks/batch -> 32 adds/address).
    __shared__ float lds_r[M];
    for (int i = tid; i < M; i += THREADS) lds_r[i] = 0.f;
    __syncthreads();
    atomicAdd(&lds_r[f0 + 0], racc0.x);
    atomicAdd(&lds_r[f0 + 1], racc0.y);
    atomicAdd(&lds_r[f0 + 2], racc0.z);
    atomicAdd(&lds_r[f0 + 3], racc0.w);
    atomicAdd(&lds_r[f1 + 0], racc1.x);
    atomicAdd(&lds_r[f1 + 1], racc1.y);
    atomicAdd(&lds_r[f1 + 2], racc1.z);
    atomicAdd(&lds_r[f1 + 3], racc1.w);
    __syncthreads();
    for (int i = tid; i < M; i += THREADS)
        atomicAdd(&r_out[bm + i], lds_r[i]);
}

// Kernel B: content addressing. One block per batch.
// cos = dot / (max(||row||,eps) * max(||k||,eps)); w_c = softmax_N(beta*cos)
__global__ __launch_bounds__(THREADS) void ntm_softmax(
    const float* __restrict__ k_t, const float* __restrict__ beta_t,
    const float* __restrict__ dots_ws, const float* __restrict__ ss_ws,
    float* __restrict__ wc_out)
{
    const int b = blockIdx.x;
    const int tid = threadIdx.x, lane = tid & 63, wave = tid >> 6;
    __shared__ float redA[WAVES], redB[WAVES], redC[WAVES];

    // ||k||^2
    float s = 0.f;
    for (int i = tid; i < M; i += THREADS) {
        const float v = k_t[(size_t)b * M + i];
        s += v * v;
    }
    #pragma unroll
    for (int off = 32; off; off >>= 1) s += __shfl_xor(s, off);
    if (lane == 0) redA[wave] = s;
    __syncthreads();
    float kn2 = 0.f;
    for (int wv = 0; wv < WAVES; ++wv) kn2 += redA[wv];
    const float inv_kn = 1.0f / fmaxf(sqrtf(kn2), EPS);
    const float beta = beta_t[b];

    constexpr int PER = N / THREADS;  // 8
    float lg[PER];
    float lmax = -INFINITY;
    #pragma unroll
    for (int j = 0; j < PER; ++j) {
        const int n = j * THREADS + tid;
        const float dot = dots_ws[(size_t)b * N + n];
        const float nrm = fmaxf(sqrtf(ss_ws[(size_t)b * N + n]), EPS);
        const float v = beta * (dot / nrm) * inv_kn;
        lg[j] = v;
        lmax = fmaxf(lmax, v);
    }
    #pragma unroll
    for (int off = 32; off; off >>= 1) lmax = fmaxf(lmax, __shfl_xor(lmax, off));
    if (lane == 0) redB[wave] = lmax;
    __syncthreads();
    lmax = redB[0];
    for (int wv = 1; wv < WAVES; ++wv) lmax = fmaxf(lmax, redB[wv]);

    float lsum = 0.f;
    #pragma unroll
    for (int j = 0; j < PER; ++j) {
        lg[j] = expf(lg[j] - lmax);
        lsum += lg[j];
    }
    #pragma unroll
    for (int off = 32; off; off >>= 1) lsum += __shfl_xor(lsum, off);
    if (lane == 0) redC[wave] = lsum;
    __syncthreads();
    float tot = 0.f;
    for (int wv = 0; wv < WAVES; ++wv) tot += redC[wv];
    const float inv = 1.0f / tot;
    #pragma unroll
    for (int j = 0; j < PER; ++j) {
        const int n = j * THREADS + tid;
        wc_out[(size_t)b * N + n] = lg[j] * inv;
    }
}

}  // namespace

extern "C" void kernel_launch(void* const* d_in, const int* in_sizes, int n_in,
                              void* d_out, int out_size, void* d_ws, size_t ws_size,
                              hipStream_t stream) {
    const float* memory = (const float*)d_in[0];
    const float* w_t    = (const float*)d_in[1];
    const float* e_t    = (const float*)d_in[2];
    const float* a_t    = (const float*)d_in[3];
    const float* k_t    = (const float*)d_in[4];
    const float* beta_t = (const float*)d_in[5];

    // Output layout (flat, return order): r (B*M), new_mem (B*N*M), w_c (B*N)
    float* r_out   = (float*)d_out;
    float* new_mem = r_out + (size_t)B * M;
    float* wc_out  = new_mem + (size_t)B * N * M;

    // Workspace: dots (B*N), ss (B*N)
    float* dots_ws = (float*)d_ws;
    float* ss_ws   = dots_ws + (size_t)B * N;

    // r region is poisoned 0xAA by the harness; zero it (atomics accumulate).
    (void)hipMemsetAsync(r_out, 0, (size_t)B * M * sizeof(float), stream);

    const dim3 gridA(B * CHUNKS_PER_B);  // 2048 blocks
    ntm_main<<<gridA, THREADS, 0, stream>>>(memory, w_t, e_t, a_t, k_t,
                                            r_out, new_mem, dots_ws, ss_ws);
    ntm_softmax<<<B, THREADS, 0, stream>>>(k_t, beta_t, dots_ws, ss_ws, wc_out);
}

// Round 5
// 451.948 us; speedup vs baseline: 1.1006x; 1.1006x over previous
//
#include <hip/hip_runtime.h>
#include <math.h>

namespace {

constexpr int B = 64;
constexpr int N = 2048;
constexpr int M = 512;
constexpr float EPS = 1e-8f;

constexpr int THREADS = 256;
constexpr int WAVES = THREADS / 64;          // 4
constexpr int ROWS_PER_BLOCK = 64;
constexpr int ROWS_PER_WAVE = ROWS_PER_BLOCK / WAVES;  // 16
constexpr int CHUNKS_PER_B = N / ROWS_PER_BLOCK;       // 32

typedef float vfloat4 __attribute__((ext_vector_type(4)));

// Kernel A: streaming pass over memory.
//   new_mem = memory*(1 - w*e) + w*a   (written out, nontemporal)
//   dots[b,n] = <new_mem[b,n,:], k[b,:]>
//   ss[b,n]   = <new_mem[b,n,:], new_mem[b,n,:]>
//   r[b,m]   += w[b,n]*new_mem[b,n,m]
//
// v4: depth-4 software pipeline with NAMED register buffers (no arrays!).
// v3 lesson: rotating pm[4] arrays + launch_bounds(256,4) got demoted to
// scratch (VGPR_Count=64 < live-range need) -> +300 MB of spill traffic
// (WRITE 269->459 MB). Hand-unrolled rows with literal indices and named
// vfloat4 buffers are immune to that demotion. Keep v0's proven-clean
// epilogue (WRITE was exactly logical 269 MB in R0).
// v4b: macro param renamed w->wgt (was capturing the .w component accessor).
__global__ __launch_bounds__(THREADS) void ntm_main(
    const float* __restrict__ memory, const float* __restrict__ w_t,
    const float* __restrict__ e_t, const float* __restrict__ a_t,
    const float* __restrict__ k_t,
    float* __restrict__ r_out, float* __restrict__ new_mem,
    float* __restrict__ dots_ws, float* __restrict__ ss_ws)
{
    const int tid  = threadIdx.x;
    const int lane = tid & 63;
    const int wave = tid >> 6;

    const int b     = blockIdx.x / CHUNKS_PER_B;
    const int chunk = blockIdx.x % CHUNKS_PER_B;
    const int row0  = chunk * ROWS_PER_BLOCK + wave * ROWS_PER_WAVE;

    // Each lane owns 8 m-columns: floats [f0..f0+3] and [f1..f1+3]
    const int f0 = lane * 4;        // covers m 0..255 across the wave
    const int f1 = 256 + lane * 4;  // covers m 256..511

    const size_t bm = (size_t)b * M;
    const vfloat4 e0 = *(const vfloat4*)(e_t + bm + f0);
    const vfloat4 e1 = *(const vfloat4*)(e_t + bm + f1);
    const vfloat4 a0 = *(const vfloat4*)(a_t + bm + f0);
    const vfloat4 a1 = *(const vfloat4*)(a_t + bm + f1);
    const vfloat4 k0 = *(const vfloat4*)(k_t + bm + f0);
    const vfloat4 k1 = *(const vfloat4*)(k_t + bm + f1);

    const size_t wbase = (size_t)b * N + row0;
    const float* __restrict__ mrow = memory  + wbase * (size_t)M;
    float* __restrict__       orow = new_mem + wbase * (size_t)M;

    // 16 named wave-uniform scalars -> SGPRs (free), not an indexable array.
    const float w0  = w_t[wbase +  0], w1  = w_t[wbase +  1];
    const float w2  = w_t[wbase +  2], w3  = w_t[wbase +  3];
    const float w4  = w_t[wbase +  4], w5  = w_t[wbase +  5];
    const float w6  = w_t[wbase +  6], w7  = w_t[wbase +  7];
    const float w8  = w_t[wbase +  8], w9  = w_t[wbase +  9];
    const float w10 = w_t[wbase + 10], w11 = w_t[wbase + 11];
    const float w12 = w_t[wbase + 12], w13 = w_t[wbase + 13];
    const float w14 = w_t[wbase + 14], w15 = w_t[wbase + 15];

    vfloat4 racc0 = (vfloat4)0.f;
    vfloat4 racc1 = (vfloat4)0.f;

    // Named pipeline buffers: 4 rows in flight (8 float4 loads).
    vfloat4 p0A, p1A, p0B, p1B, p0C, p1C, p0D, p1D;

#define PREF(q0, q1, ri)                                            \
    q0 = *(const vfloat4*)(mrow + (size_t)(ri) * M + f0);           \
    q1 = *(const vfloat4*)(mrow + (size_t)(ri) * M + f1);

    PREF(p0A, p1A, 0)
    PREF(p0B, p1B, 1)
    PREF(p0C, p1C, 2)
    PREF(p0D, p1D, 3)

#define DOROW(q0, q1, ri, wgt) {                                            \
    const vfloat4 m0 = q0;                                                  \
    const vfloat4 m1 = q1;                                                  \
    if ((ri) + 4 < ROWS_PER_WAVE) { PREF(q0, q1, (ri) + 4) }                \
    vfloat4 nm0, nm1;                                                       \
    nm0.x = fmaf(wgt, fmaf(-m0.x, e0.x, a0.x), m0.x);                       \
    nm0.y = fmaf(wgt, fmaf(-m0.y, e0.y, a0.y), m0.y);                       \
    nm0.z = fmaf(wgt, fmaf(-m0.z, e0.z, a0.z), m0.z);                       \
    nm0.w = fmaf(wgt, fmaf(-m0.w, e0.w, a0.w), m0.w);                       \
    nm1.x = fmaf(wgt, fmaf(-m1.x, e1.x, a1.x), m1.x);                       \
    nm1.y = fmaf(wgt, fmaf(-m1.y, e1.y, a1.y), m1.y);                       \
    nm1.z = fmaf(wgt, fmaf(-m1.z, e1.z, a1.z), m1.z);                       \
    nm1.w = fmaf(wgt, fmaf(-m1.w, e1.w, a1.w), m1.w);                       \
    __builtin_nontemporal_store(nm0, (vfloat4*)(orow + (size_t)(ri) * M + f0)); \
    __builtin_nontemporal_store(nm1, (vfloat4*)(orow + (size_t)(ri) * M + f1)); \
    float dot = nm0.x * k0.x + nm0.y * k0.y + nm0.z * k0.z + nm0.w * k0.w   \
              + nm1.x * k1.x + nm1.y * k1.y + nm1.z * k1.z + nm1.w * k1.w;  \
    float ssv = nm0.x * nm0.x + nm0.y * nm0.y + nm0.z * nm0.z + nm0.w * nm0.w \
              + nm1.x * nm1.x + nm1.y * nm1.y + nm1.z * nm1.z + nm1.w * nm1.w; \
    racc0.x = fmaf(wgt, nm0.x, racc0.x);                                    \
    racc0.y = fmaf(wgt, nm0.y, racc0.y);                                    \
    racc0.z = fmaf(wgt, nm0.z, racc0.z);                                    \
    racc0.w = fmaf(wgt, nm0.w, racc0.w);                                    \
    racc1.x = fmaf(wgt, nm1.x, racc1.x);                                    \
    racc1.y = fmaf(wgt, nm1.y, racc1.y);                                    \
    racc1.z = fmaf(wgt, nm1.z, racc1.z);                                    \
    racc1.w = fmaf(wgt, nm1.w, racc1.w);                                    \
    dot += __shfl_xor(dot, 32); ssv += __shfl_xor(ssv, 32);                 \
    dot += __shfl_xor(dot, 16); ssv += __shfl_xor(ssv, 16);                 \
    dot += __shfl_xor(dot,  8); ssv += __shfl_xor(ssv,  8);                 \
    dot += __shfl_xor(dot,  4); ssv += __shfl_xor(ssv,  4);                 \
    dot += __shfl_xor(dot,  2); ssv += __shfl_xor(ssv,  2);                 \
    dot += __shfl_xor(dot,  1); ssv += __shfl_xor(ssv,  1);                 \
    if (lane == 0) {                                                        \
        dots_ws[wbase + (ri)] = dot;                                        \
        ss_ws[wbase + (ri)]   = ssv;                                        \
    } }

    DOROW(p0A, p1A,  0, w0)
    DOROW(p0B, p1B,  1, w1)
    DOROW(p0C, p1C,  2, w2)
    DOROW(p0D, p1D,  3, w3)
    DOROW(p0A, p1A,  4, w4)
    DOROW(p0B, p1B,  5, w5)
    DOROW(p0C, p1C,  6, w6)
    DOROW(p0D, p1D,  7, w7)
    DOROW(p0A, p1A,  8, w8)
    DOROW(p0B, p1B,  9, w9)
    DOROW(p0C, p1C, 10, w10)
    DOROW(p0D, p1D, 11, w11)
    DOROW(p0A, p1A, 12, w12)
    DOROW(p0B, p1B, 13, w13)
    DOROW(p0C, p1C, 14, w14)
    DOROW(p0D, p1D, 15, w15)

#undef DOROW
#undef PREF

    // Combine r partials across the 4 waves in LDS, then one global
    // atomicAdd per element per block (32 blocks/batch -> 32 adds/address).
    __shared__ float lds_r[M];
    for (int i = tid; i < M; i += THREADS) lds_r[i] = 0.f;
    __syncthreads();
    atomicAdd(&lds_r[f0 + 0], racc0.x);
    atomicAdd(&lds_r[f0 + 1], racc0.y);
    atomicAdd(&lds_r[f0 + 2], racc0.z);
    atomicAdd(&lds_r[f0 + 3], racc0.w);
    atomicAdd(&lds_r[f1 + 0], racc1.x);
    atomicAdd(&lds_r[f1 + 1], racc1.y);
    atomicAdd(&lds_r[f1 + 2], racc1.z);
    atomicAdd(&lds_r[f1 + 3], racc1.w);
    __syncthreads();
    for (int i = tid; i < M; i += THREADS)
        atomicAdd(&r_out[bm + i], lds_r[i]);
}

// Kernel B: content addressing. One block per batch.
// cos = dot / (max(||row||,eps) * max(||k||,eps)); w_c = softmax_N(beta*cos)
__global__ __launch_bounds__(THREADS) void ntm_softmax(
    const float* __restrict__ k_t, const float* __restrict__ beta_t,
    const float* __restrict__ dots_ws, const float* __restrict__ ss_ws,
    float* __restrict__ wc_out)
{
    const int b = blockIdx.x;
    const int tid = threadIdx.x, lane = tid & 63, wave = tid >> 6;
    __shared__ float redA[WAVES], redB[WAVES], redC[WAVES];

    // ||k||^2
    float s = 0.f;
    for (int i = tid; i < M; i += THREADS) {
        const float v = k_t[(size_t)b * M + i];
        s += v * v;
    }
    #pragma unroll
    for (int off = 32; off; off >>= 1) s += __shfl_xor(s, off);
    if (lane == 0) redA[wave] = s;
    __syncthreads();
    float kn2 = 0.f;
    for (int wv = 0; wv < WAVES; ++wv) kn2 += redA[wv];
    const float inv_kn = 1.0f / fmaxf(sqrtf(kn2), EPS);
    const float beta = beta_t[b];

    constexpr int PER = N / THREADS;  // 8
    float lg[PER];
    float lmax = -INFINITY;
    #pragma unroll
    for (int j = 0; j < PER; ++j) {
        const int n = j * THREADS + tid;
        const float dot = dots_ws[(size_t)b * N + n];
        const float nrm = fmaxf(sqrtf(ss_ws[(size_t)b * N + n]), EPS);
        const float v = beta * (dot / nrm) * inv_kn;
        lg[j] = v;
        lmax = fmaxf(lmax, v);
    }
    #pragma unroll
    for (int off = 32; off; off >>= 1) lmax = fmaxf(lmax, __shfl_xor(lmax, off));
    if (lane == 0) redB[wave] = lmax;
    __syncthreads();
    lmax = redB[0];
    for (int wv = 1; wv < WAVES; ++wv) lmax = fmaxf(lmax, redB[wv]);

    float lsum = 0.f;
    #pragma unroll
    for (int j = 0; j < PER; ++j) {
        lg[j] = expf(lg[j] - lmax);
        lsum += lg[j];
    }
    #pragma unroll
    for (int off = 32; off; off >>= 1) lsum += __shfl_xor(lsum, off);
    if (lane == 0) redC[wave] = lsum;
    __syncthreads();
    float tot = 0.f;
    for (int wv = 0; wv < WAVES; ++wv) tot += redC[wv];
    const float inv = 1.0f / tot;
    #pragma unroll
    for (int j = 0; j < PER; ++j) {
        const int n = j * THREADS + tid;
        wc_out[(size_t)b * N + n] = lg[j] * inv;
    }
}

}  // namespace

extern "C" void kernel_launch(void* const* d_in, const int* in_sizes, int n_in,
                              void* d_out, int out_size, void* d_ws, size_t ws_size,
                              hipStream_t stream) {
    const float* memory = (const float*)d_in[0];
    const float* w_t    = (const float*)d_in[1];
    const float* e_t    = (const float*)d_in[2];
    const float* a_t    = (const float*)d_in[3];
    const float* k_t    = (const float*)d_in[4];
    const float* beta_t = (const float*)d_in[5];

    // Output layout (flat, return order): r (B*M), new_mem (B*N*M), w_c (B*N)
    float* r_out   = (float*)d_out;
    float* new_mem = r_out + (size_t)B * M;
    float* wc_out  = new_mem + (size_t)B * N * M;

    // Workspace: dots (B*N), ss (B*N)
    float* dots_ws = (float*)d_ws;
    float* ss_ws   = dots_ws + (size_t)B * N;

    // r region is poisoned 0xAA by the harness; zero it (atomics accumulate).
    (void)hipMemsetAsync(r_out, 0, (size_t)B * M * sizeof(float), stream);

    const dim3 gridA(B * CHUNKS_PER_B);  // 2048 blocks
    ntm_main<<<gridA, THREADS, 0, stream>>>(memory, w_t, e_t, a_t, k_t,
                                            r_out, new_mem, dots_ws, ss_ws);
    ntm_softmax<<<B, THREADS, 0, stream>>>(k_t, beta_t, dots_ws, ss_ws, wc_out);
}